// Round 7
// baseline (118.186 us; speedup 1.0000x reference)
//
#include <hip/hip_runtime.h>
#include <hip/hip_bf16.h>
#include <stdint.h>

typedef __bf16 bf16_t;
typedef __bf16 bf16x8 __attribute__((ext_vector_type(8)));
typedef __bf16 bf16x4 __attribute__((ext_vector_type(4)));
typedef __bf16 bf16x2 __attribute__((ext_vector_type(2)));
typedef float f32x4 __attribute__((ext_vector_type(4)));
typedef float f32x16 __attribute__((ext_vector_type(16)));
typedef uint32_t u32;
typedef uint32_t u32x4 __attribute__((ext_vector_type(4)));

typedef __attribute__((address_space(1))) void as1void;
typedef __attribute__((address_space(3))) void as3void;

#define LOG2E 1.44269504088896340736f

__device__ __forceinline__ void gll16(const void* g, void* l) {
  __builtin_amdgcn_global_load_lds((as1void*)g, (as3void*)l, 16, 0, 0);
}

// pack two f32 -> u32 of 2 bf16 (compiler emits v_cvt_pk_bf16_f32)
__device__ __forceinline__ u32 pack2(float a, float b) {
  bf16x2 t = {(bf16_t)a, (bf16_t)b};
  return __builtin_bit_cast(u32, t);
}

// ---------------- prep: W_eff = W + 2.0 * B @ A (both linears fused) -------
__global__ void prep_weff2(const float* __restrict__ W_attn, const float* __restrict__ B_attn,
                           const float* __restrict__ A_attn, const float* __restrict__ W_proj,
                           const float* __restrict__ B_proj, const float* __restrict__ A_proj,
                           bf16_t* __restrict__ WaE, bf16_t* __restrict__ WpE) {
  int idx = blockIdx.x * 256 + threadIdx.x;  // 0..4194303
  const float *W, *Bm, *Am;
  bf16_t* dst;
  if (idx < 3145728) {
    W = W_attn; Bm = B_attn; Am = A_attn; dst = WaE;
  } else {
    idx -= 3145728;
    W = W_proj; Bm = B_proj; Am = A_proj; dst = WpE;
  }
  int o = idx >> 10, c = idx & 1023;
  float acc = W[idx];
#pragma unroll
  for (int r = 0; r < 8; ++r)
    acc += 2.0f * Bm[o * 8 + r] * Am[r * 1024 + c];
  dst[idx] = (bf16_t)acc;
}

__global__ void cast_bf4(const float4* __restrict__ X, bf16x4* __restrict__ Xb, int n4) {
  int i = blockIdx.x * 256 + threadIdx.x;
  if (i < n4) {
    float4 v = X[i];
    bf16x4 o = {(bf16_t)v.x, (bf16_t)v.y, (bf16_t)v.z, (bf16_t)v.w};
    Xb[i] = o;
  }
}

// ---------------- GEMM: C[m][n] = sum_k A[m][k] * Bt[n][k] + bias[n] -------
// 128x128 tile, BK=64, 4 waves. global_load_lds staging, pre-swizzled source.
template <bool QKV>
__global__ __launch_bounds__(256, 3) void gemm_bt(
    const bf16_t* __restrict__ A, const bf16_t* __restrict__ Bt,
    const float* __restrict__ bias,
    bf16_t* __restrict__ Qb, bf16_t* __restrict__ Kb, bf16_t* __restrict__ Vb,
    float* __restrict__ Out) {
  __shared__ bf16_t Als[128][64];
  __shared__ bf16_t Bls[128][64];
  const int m0 = blockIdx.x * 128;
  const int n0 = blockIdx.y * 128;
  const int tid = threadIdx.x;
  const int lane = tid & 63;
  const int w = tid >> 6;
  const int wm = w >> 1, wn = w & 1;
  const int lr = lane & 15, g = lane >> 4;
  const int sw = (lane & 7) << 3;
  const int srow = lane >> 3;
  const int soff = ((lane & 7) ^ srow) * 8;

  f32x4 acc[4][4] = {};

  for (int k0 = 0; k0 < 1024; k0 += 64) {
#pragma unroll
    for (int c = 0; c < 4; ++c) {
      int r = w * 32 + c * 8 + srow;
      gll16(A + (size_t)(m0 + r) * 1024 + k0 + soff, &Als[w * 32 + c * 8][0]);
      gll16(Bt + (size_t)(n0 + r) * 1024 + k0 + soff, &Bls[w * 32 + c * 8][0]);
    }
    __syncthreads();
#pragma unroll
    for (int ks = 0; ks < 2; ++ks) {
      bf16x8 af[4], bfv[4];
#pragma unroll
      for (int i = 0; i < 4; ++i)
        af[i] = *(const bf16x8*)&Als[wm * 64 + i * 16 + lr][(ks * 32 + g * 8) ^ sw];
#pragma unroll
      for (int j = 0; j < 4; ++j)
        bfv[j] = *(const bf16x8*)&Bls[wn * 64 + j * 16 + lr][(ks * 32 + g * 8) ^ sw];
#pragma unroll
      for (int i = 0; i < 4; ++i)
#pragma unroll
        for (int j = 0; j < 4; ++j)
          acc[i][j] = __builtin_amdgcn_mfma_f32_16x16x32_bf16(af[i], bfv[j], acc[i][j], 0, 0, 0);
    }
    __syncthreads();
  }

#pragma unroll
  for (int i = 0; i < 4; ++i) {
#pragma unroll
    for (int j = 0; j < 4; ++j) {
#pragma unroll
      for (int e = 0; e < 4; ++e) {
        int m = m0 + wm * 64 + i * 16 + g * 4 + e;
        int n = n0 + wn * 64 + j * 16 + lr;
        float v = acc[i][j][e] + bias[n];
        if (QKV) {
          int b = m >> 11, t = m & 2047;
          int which = n >> 10, hn = n & 1023;
          int h = hn >> 6, d = hn & 63;
          bf16_t* dst = (which == 0) ? Qb : (which == 1) ? Kb : Vb;
          dst[(((size_t)(b * 16 + h)) * 2048 + t) * 64 + d] = (bf16_t)v;
        } else {
          Out[(size_t)m * 1024 + n] = v;
        }
      }
    }
  }
}

// ---------------- flash attention, causal, hd=64 ---------------------------
// QBLK=128 (4 waves x 32 q-rows), KVBLK=128, 32x32x16 MFMA, P in registers.
__global__ __launch_bounds__(256, 2) void attn_fwd(
    const bf16_t* __restrict__ Qb, const bf16_t* __restrict__ Kb,
    const bf16_t* __restrict__ Vb, bf16_t* __restrict__ Ob) {
  __shared__ bf16_t Kls[128][64];   // K tile, chunk ^= row&7
  __shared__ bf16_t Vt[64][128];    // V^T [d][k], chunk key = (d&7)^((d>>2)&7)

  // XCD-aware, pair-balanced mapping
  int id = blockIdx.x;
  int xcd = id & 7, j = id >> 3;
  int lo = j & 31, hi2 = j >> 5;
  int bh = xcd * 4 + (lo & 3);
  int qb = hi2 ? 15 - (lo >> 2) : (lo >> 2);
  int b = bh >> 4, h = bh & 15;

  const int tid = threadIdx.x, lane = tid & 63, w = tid >> 6;
  const int q32 = lane & 31;     // q-col owned by this lane
  const int hi = lane >> 5;      // k-half
  const int ksw = (q32 & 7) << 3;
  const int vkey = ((q32 & 7) ^ (q32 >> 2)) << 3;  // same for both d-blocks
  const bf16_t* Qp = Qb + (size_t)bh * 2048 * 64;
  const bf16_t* Kp = Kb + (size_t)bh * 2048 * 64;
  const bf16_t* Vp = Vb + (size_t)bh * 2048 * 64;
  const float sc = 0.125f * LOG2E;

  const int q0 = qb * 128;
  const int qrow = q0 + w * 32 + q32;

  // Q-frag (B-operand): lane holds Q[q=qrow][d = ds*16 + hi*8 + e]
  bf16x8 qf[4];
#pragma unroll
  for (int ds = 0; ds < 4; ++ds)
    qf[ds] = *(const bf16x8*)(Qp + (size_t)qrow * 64 + ds * 16 + hi * 8);

  float m_run = -3e38f, l_run = 0.f;
  f32x16 o_acc[2] = {};
  const int ktiles = qb + 1;

  for (int kt = 0; kt < ktiles; ++kt) {
    const int k0 = kt * 128;
    const bool lastt = (kt == ktiles - 1);
    const int nfa = lastt ? (w + 1) : 4;  // causal: skip fully-masked k-frags
    __syncthreads();

    // ---- stage K via global_load_lds (pre-swizzled source) ----
#pragma unroll
    for (int c = 0; c < 4; ++c) {
      int rb = w * 32 + c * 8;
      gll16(Kp + (size_t)(k0 + rb + (lane >> 3)) * 64 + ((lane & 7) ^ (lane >> 3)) * 8,
            &Kls[rb][0]);
    }

    // ---- stage V^T: per-thread 8k x 4d reg transpose via v_perm ----
    {
      int kbase = (tid >> 4) * 8;   // 0..120
      int dbase = (tid & 15) * 4;   // 0..60
      uint2 rowv[8];
#pragma unroll
      for (int r = 0; r < 8; ++r)
        rowv[r] = *(const uint2*)(Vp + (size_t)(k0 + kbase + r) * 64 + dbase);
#pragma unroll
      for (int dd = 0; dd < 4; ++dd) {
        u32 sel = (dd & 1) ? 0x07060302u : 0x05040100u;
        u32 a0 = (dd >> 1) ? rowv[0].y : rowv[0].x;
        u32 a1 = (dd >> 1) ? rowv[1].y : rowv[1].x;
        u32 a2 = (dd >> 1) ? rowv[2].y : rowv[2].x;
        u32 a3 = (dd >> 1) ? rowv[3].y : rowv[3].x;
        u32 a4 = (dd >> 1) ? rowv[4].y : rowv[4].x;
        u32 a5 = (dd >> 1) ? rowv[5].y : rowv[5].x;
        u32 a6 = (dd >> 1) ? rowv[6].y : rowv[6].x;
        u32 a7 = (dd >> 1) ? rowv[7].y : rowv[7].x;
        int4 val;
        val.x = __builtin_amdgcn_perm(a1, a0, sel);
        val.y = __builtin_amdgcn_perm(a3, a2, sel);
        val.z = __builtin_amdgcn_perm(a5, a4, sel);
        val.w = __builtin_amdgcn_perm(a7, a6, sel);
        int d = dbase + dd;
        int key = ((d & 7) ^ ((d >> 2) & 7)) << 3;
        *(int4*)&Vt[d][kbase ^ key] = val;
      }
    }
    __syncthreads();

    // ---- QK^T (swapped): S^T[k][q], 32x32 frags; lane owns q-col qrow ----
    f32x16 s[4] = {};
#pragma unroll
    for (int fa = 0; fa < 4; ++fa) {
      if (fa < nfa) {
#pragma unroll
        for (int ds = 0; ds < 4; ++ds) {
          bf16x8 kf = *(const bf16x8*)&Kls[fa * 32 + q32][(ds * 16 + hi * 8) ^ ksw];
          s[fa] = __builtin_amdgcn_mfma_f32_32x32x16_bf16(kf, qf[ds], s[fa], 0, 0, 0);
        }
      }
    }

    // ---- softmax: scale + mask + lane-local max (+1 shfl) ----
    float mloc = -3e38f;
#pragma unroll
    for (int fa = 0; fa < 4; ++fa) {
      if (fa < nfa) {
#pragma unroll
        for (int r = 0; r < 16; ++r) {
          float v = s[fa][r] * sc;
          if (lastt && fa == w) {
            int km = (r & 3) + 8 * (r >> 2) + 4 * hi;
            if (km > q32) v = -3e38f;
          }
          s[fa][r] = v;
          mloc = fmaxf(mloc, v);
        }
      }
    }
    mloc = fmaxf(mloc, __shfl_xor(mloc, 32, 64));
    if (!__all(mloc <= m_run + 8.0f)) {  // defer-max (T13)
      float mnew = fmaxf(m_run, mloc);
      float rs = __builtin_amdgcn_exp2f(m_run - mnew);
      m_run = mnew;
      l_run *= rs;
      o_acc[0] *= rs;
      o_acc[1] *= rs;
    }

    // ---- exp + in-register P-frag build (pack + shfl_xor exchange) + PV ----
    // Lane (q32,hi) holds S rows k = (r&3)+8*(r>>2)+4*hi of this 32-block.
    // PV B-frag needs k = hi*8+e (slice0) and 16+hi*8+e (slice1).
    //   hi=0: keep x0,x1 (k0-3) as words 0,1; import partner x0,x1 (k4-7).
    //   hi=1: import partner x2,x3 (k8-11) as words 0,1; keep x2,x3 (k12-15).
    float lsum = 0.f;
#pragma unroll
    for (int fa = 0; fa < 4; ++fa) {
      if (fa < nfa) {
        float p[16];
#pragma unroll
        for (int r = 0; r < 16; ++r) {
          p[r] = __builtin_amdgcn_exp2f(s[fa][r] - m_run);
          lsum += p[r];
        }
        u32 x0 = pack2(p[0], p[1]),   x1 = pack2(p[2], p[3]);
        u32 x2 = pack2(p[4], p[5]),   x3 = pack2(p[6], p[7]);
        u32 y0 = pack2(p[8], p[9]),   y1 = pack2(p[10], p[11]);
        u32 y2 = pack2(p[12], p[13]), y3 = pack2(p[14], p[15]);
        // send exactly what the partner (lane^32) needs; receive ours
        u32 z0 = hi ? x0 : x2;
        u32 z1 = hi ? x1 : x3;
        u32 z2 = hi ? y0 : y2;
        u32 z3 = hi ? y1 : y3;
        z0 = (u32)__shfl_xor((int)z0, 32, 64);
        z1 = (u32)__shfl_xor((int)z1, 32, 64);
        z2 = (u32)__shfl_xor((int)z2, 32, 64);
        z3 = (u32)__shfl_xor((int)z3, 32, 64);
        u32x4 pw0 = hi ? (u32x4){z0, z1, x2, x3} : (u32x4){x0, x1, z0, z1};
        u32x4 pw1 = hi ? (u32x4){z2, z3, y2, y3} : (u32x4){y0, y1, z2, z3};
        bf16x8 P0 = __builtin_bit_cast(bf16x8, pw0);
        bf16x8 P1 = __builtin_bit_cast(bf16x8, pw1);
#pragma unroll
        for (int db = 0; db < 2; ++db) {
          int d = db * 32 + q32;
          bf16x8 vf0 = *(const bf16x8*)&Vt[d][(fa * 32 + hi * 8) ^ vkey];
          o_acc[db] = __builtin_amdgcn_mfma_f32_32x32x16_bf16(vf0, P0, o_acc[db], 0, 0, 0);
          bf16x8 vf1 = *(const bf16x8*)&Vt[d][(fa * 32 + 16 + hi * 8) ^ vkey];
          o_acc[db] = __builtin_amdgcn_mfma_f32_32x32x16_bf16(vf1, P1, o_acc[db], 0, 0, 0);
        }
      }
    }
    lsum += __shfl_xor(lsum, 32, 64);
    l_run += lsum;
  }  // kt

  // ---- epilogue: lane owns column q=qrow; d = db*32 + rg*8 + hi*4 + 0..3 ----
  float inv = 1.0f / l_run;
  bf16_t* obase = Ob + ((size_t)(b * 2048 + qrow)) * 1024 + h * 64;
#pragma unroll
  for (int db = 0; db < 2; ++db) {
#pragma unroll
    for (int rg = 0; rg < 4; ++rg) {
      bf16x4 ov = {(bf16_t)(o_acc[db][rg * 4 + 0] * inv),
                   (bf16_t)(o_acc[db][rg * 4 + 1] * inv),
                   (bf16_t)(o_acc[db][rg * 4 + 2] * inv),
                   (bf16_t)(o_acc[db][rg * 4 + 3] * inv)};
      *(bf16x4*)(obase + db * 32 + rg * 8 + hi * 4) = ov;
    }
  }
}

// ---------------------------------------------------------------------------
extern "C" void kernel_launch(void* const* d_in, const int* in_sizes, int n_in,
                              void* d_out, int out_size, void* d_ws, size_t ws_size,
                              hipStream_t stream) {
  const float* x      = (const float*)d_in[0];
  const float* W_attn = (const float*)d_in[1];
  const float* b_attn = (const float*)d_in[2];
  const float* A_attn = (const float*)d_in[3];
  const float* B_attn = (const float*)d_in[4];
  const float* W_proj = (const float*)d_in[5];
  const float* b_proj = (const float*)d_in[6];
  const float* A_proj = (const float*)d_in[7];
  const float* B_proj = (const float*)d_in[8];
  float* out = (float*)d_out;

  char* ws = (char*)d_ws;
  bf16_t* WaE = (bf16_t*)(ws);               // 3072*1024*2
  bf16_t* WpE = (bf16_t*)(ws + 6291456);     // 1024*1024*2
  bf16_t* Xb  = (bf16_t*)(ws + 8388608);     // 4096*1024*2
  bf16_t* Qb  = (bf16_t*)(ws + 16777216);    // [B*H][T][64]
  bf16_t* Kb  = (bf16_t*)(ws + 25165824);
  bf16_t* Vb  = (bf16_t*)(ws + 33554432);
  bf16_t* Ob  = (bf16_t*)(ws + 41943040);    // [B*T][C] bf16

  prep_weff2<<<16384, 256, 0, stream>>>(W_attn, B_attn, A_attn, W_proj, B_proj, A_proj, WaE, WpE);
  cast_bf4<<<4096, 256, 0, stream>>>((const float4*)x, (bf16x4*)Xb, 1048576);

  gemm_bt<true><<<dim3(32, 24), 256, 0, stream>>>(Xb, WaE, b_attn, Qb, Kb, Vb, nullptr);
  attn_fwd<<<512, 256, 0, stream>>>(Qb, Kb, Vb, Ob);
  gemm_bt<false><<<dim3(32, 8), 256, 0, stream>>>(Ob, WpE, b_proj, nullptr, nullptr, nullptr, out);
}

// Round 8
// 112.414 us; speedup vs baseline: 1.0514x; 1.0514x over previous
//
#include <hip/hip_runtime.h>
#include <hip/hip_bf16.h>
#include <stdint.h>

typedef __bf16 bf16_t;
typedef __bf16 bf16x8 __attribute__((ext_vector_type(8)));
typedef __bf16 bf16x4 __attribute__((ext_vector_type(4)));
typedef __bf16 bf16x2 __attribute__((ext_vector_type(2)));
typedef float f32x4 __attribute__((ext_vector_type(4)));
typedef float f32x16 __attribute__((ext_vector_type(16)));
typedef uint32_t u32;
typedef uint32_t u32x4 __attribute__((ext_vector_type(4)));

typedef __attribute__((address_space(1))) void as1void;
typedef __attribute__((address_space(3))) void as3void;

#define LOG2E 1.44269504088896340736f

__device__ __forceinline__ void gll16(const void* g, void* l) {
  __builtin_amdgcn_global_load_lds((as1void*)g, (as3void*)l, 16, 0, 0);
}

// pack two f32 -> u32 of 2 bf16 (compiler emits v_cvt_pk_bf16_f32)
__device__ __forceinline__ u32 pack2(float a, float b) {
  bf16x2 t = {(bf16_t)a, (bf16_t)b};
  return __builtin_bit_cast(u32, t);
}

// ---------------- prep: W_eff = W + 2.0 * B @ A (both linears fused) -------
__global__ void prep_weff2(const float* __restrict__ W_attn, const float* __restrict__ B_attn,
                           const float* __restrict__ A_attn, const float* __restrict__ W_proj,
                           const float* __restrict__ B_proj, const float* __restrict__ A_proj,
                           bf16_t* __restrict__ WaE, bf16_t* __restrict__ WpE) {
  int idx = blockIdx.x * 256 + threadIdx.x;  // 0..4194303
  const float *W, *Bm, *Am;
  bf16_t* dst;
  if (idx < 3145728) {
    W = W_attn; Bm = B_attn; Am = A_attn; dst = WaE;
  } else {
    idx -= 3145728;
    W = W_proj; Bm = B_proj; Am = A_proj; dst = WpE;
  }
  int o = idx >> 10, c = idx & 1023;
  float acc = W[idx];
#pragma unroll
  for (int r = 0; r < 8; ++r)
    acc += 2.0f * Bm[o * 8 + r] * Am[r * 1024 + c];
  dst[idx] = (bf16_t)acc;
}

__global__ void cast_bf4(const float4* __restrict__ X, bf16x4* __restrict__ Xb, int n4) {
  int i = blockIdx.x * 256 + threadIdx.x;
  if (i < n4) {
    float4 v = X[i];
    bf16x4 o = {(bf16_t)v.x, (bf16_t)v.y, (bf16_t)v.z, (bf16_t)v.w};
    Xb[i] = o;
  }
}

// ---------------- GEMM: C[m][n] = sum_k A[m][k] * Bt[n][k] + bias[n] -------
// 128x128 tile, BK=64, 4 waves. global_load_lds staging, pre-swizzled source.
template <bool QKV>
__global__ __launch_bounds__(256, 3) void gemm_bt(
    const bf16_t* __restrict__ A, const bf16_t* __restrict__ Bt,
    const float* __restrict__ bias,
    bf16_t* __restrict__ Qb, bf16_t* __restrict__ Kb, bf16_t* __restrict__ Vb,
    float* __restrict__ Out) {
  __shared__ bf16_t Als[128][64];
  __shared__ bf16_t Bls[128][64];
  const int m0 = blockIdx.x * 128;
  const int n0 = blockIdx.y * 128;
  const int tid = threadIdx.x;
  const int lane = tid & 63;
  const int w = tid >> 6;
  const int wm = w >> 1, wn = w & 1;
  const int lr = lane & 15, g = lane >> 4;
  const int sw = (lane & 7) << 3;
  const int srow = lane >> 3;
  const int soff = ((lane & 7) ^ srow) * 8;

  f32x4 acc[4][4] = {};

  for (int k0 = 0; k0 < 1024; k0 += 64) {
#pragma unroll
    for (int c = 0; c < 4; ++c) {
      int r = w * 32 + c * 8 + srow;
      gll16(A + (size_t)(m0 + r) * 1024 + k0 + soff, &Als[w * 32 + c * 8][0]);
      gll16(Bt + (size_t)(n0 + r) * 1024 + k0 + soff, &Bls[w * 32 + c * 8][0]);
    }
    __syncthreads();
#pragma unroll
    for (int ks = 0; ks < 2; ++ks) {
      bf16x8 af[4], bfv[4];
#pragma unroll
      for (int i = 0; i < 4; ++i)
        af[i] = *(const bf16x8*)&Als[wm * 64 + i * 16 + lr][(ks * 32 + g * 8) ^ sw];
#pragma unroll
      for (int j = 0; j < 4; ++j)
        bfv[j] = *(const bf16x8*)&Bls[wn * 64 + j * 16 + lr][(ks * 32 + g * 8) ^ sw];
#pragma unroll
      for (int i = 0; i < 4; ++i)
#pragma unroll
        for (int j = 0; j < 4; ++j)
          acc[i][j] = __builtin_amdgcn_mfma_f32_16x16x32_bf16(af[i], bfv[j], acc[i][j], 0, 0, 0);
    }
    __syncthreads();
  }

#pragma unroll
  for (int i = 0; i < 4; ++i) {
#pragma unroll
    for (int j = 0; j < 4; ++j) {
#pragma unroll
      for (int e = 0; e < 4; ++e) {
        int m = m0 + wm * 64 + i * 16 + g * 4 + e;
        int n = n0 + wn * 64 + j * 16 + lr;
        float v = acc[i][j][e] + bias[n];
        if (QKV) {
          int b = m >> 11, t = m & 2047;
          int which = n >> 10, hn = n & 1023;
          int h = hn >> 6, d = hn & 63;
          bf16_t* dst = (which == 0) ? Qb : (which == 1) ? Kb : Vb;
          dst[(((size_t)(b * 16 + h)) * 2048 + t) * 64 + d] = (bf16_t)v;
        } else {
          Out[(size_t)m * 1024 + n] = v;
        }
      }
    }
  }
}

// ---------------- flash attention, causal, hd=64 ---------------------------
// QBLK=128 (4 waves x 32 q-rows), KVBLK=128, 32x32x16 MFMA, P in registers.
// Double-buffered K/V tiles: issue next-tile loads before computing current.
__global__ __launch_bounds__(256, 2) void attn_fwd(
    const bf16_t* __restrict__ Qb, const bf16_t* __restrict__ Kb,
    const bf16_t* __restrict__ Vb, bf16_t* __restrict__ Ob) {
  __shared__ bf16_t Kls[2][128][64];   // K tile, chunk ^= row&7
  __shared__ bf16_t Vt[2][64][128];    // V^T [d][k], chunk key = (d&7)^((d>>2)&7)

  // XCD-aware, pair-balanced mapping
  int id = blockIdx.x;
  int xcd = id & 7, j = id >> 3;
  int lo = j & 31, hi2 = j >> 5;
  int bh = xcd * 4 + (lo & 3);
  int qb = hi2 ? 15 - (lo >> 2) : (lo >> 2);
  int b = bh >> 4, h = bh & 15;

  const int tid = threadIdx.x, lane = tid & 63, w = tid >> 6;
  const int q32 = lane & 31;     // q-col owned by this lane
  const int hi = lane >> 5;      // k-half
  const int ksw = (q32 & 7) << 3;
  const int vkey = ((q32 & 7) ^ (q32 >> 2)) << 3;  // same for both d-blocks
  const bf16_t* Qp = Qb + (size_t)bh * 2048 * 64;
  const bf16_t* Kp = Kb + (size_t)bh * 2048 * 64;
  const bf16_t* Vp = Vb + (size_t)bh * 2048 * 64;
  const float sc = 0.125f * LOG2E;

  const int q0 = qb * 128;
  const int qrow = q0 + w * 32 + q32;

  // V staging geometry (per thread)
  const int kbase = (tid >> 4) * 8;   // 0..120
  const int dbase = (tid & 15) * 4;   // 0..60
  // K staging geometry
  const int ksr = lane >> 3;
  const int kso = ((lane & 7) ^ ksr) * 8;

  // Q-frag (B-operand): lane holds Q[q=qrow][d = ds*16 + hi*8 + e]
  bf16x8 qf[4];
#pragma unroll
  for (int ds = 0; ds < 4; ++ds)
    qf[ds] = *(const bf16x8*)(Qp + (size_t)qrow * 64 + ds * 16 + hi * 8);

  float m_run = -3e38f, l_run = 0.f;
  f32x16 o_acc[2] = {};
  const int ktiles = qb + 1;

  // ---- prologue: stage tile 0 into buffer 0 ----
  {
    uint2 rowv[8];
#pragma unroll
    for (int r = 0; r < 8; ++r)
      rowv[r] = *(const uint2*)(Vp + (size_t)(kbase + r) * 64 + dbase);
#pragma unroll
    for (int c = 0; c < 4; ++c) {
      int rb = w * 32 + c * 8;
      gll16(Kp + (size_t)(rb + ksr) * 64 + kso, &Kls[0][rb][0]);
    }
#pragma unroll
    for (int dd = 0; dd < 4; ++dd) {
      u32 sel = (dd & 1) ? 0x07060302u : 0x05040100u;
      u32 a0 = (dd >> 1) ? rowv[0].y : rowv[0].x;
      u32 a1 = (dd >> 1) ? rowv[1].y : rowv[1].x;
      u32 a2 = (dd >> 1) ? rowv[2].y : rowv[2].x;
      u32 a3 = (dd >> 1) ? rowv[3].y : rowv[3].x;
      u32 a4 = (dd >> 1) ? rowv[4].y : rowv[4].x;
      u32 a5 = (dd >> 1) ? rowv[5].y : rowv[5].x;
      u32 a6 = (dd >> 1) ? rowv[6].y : rowv[6].x;
      u32 a7 = (dd >> 1) ? rowv[7].y : rowv[7].x;
      int4 val;
      val.x = __builtin_amdgcn_perm(a1, a0, sel);
      val.y = __builtin_amdgcn_perm(a3, a2, sel);
      val.z = __builtin_amdgcn_perm(a5, a4, sel);
      val.w = __builtin_amdgcn_perm(a7, a6, sel);
      int d = dbase + dd;
      int key = ((d & 7) ^ ((d >> 2) & 7)) << 3;
      *(int4*)&Vt[0][d][kbase ^ key] = val;
    }
    __syncthreads();
  }

  int cb = 0;
  for (int kt = 0; kt < ktiles; ++kt) {
    const bool lastt = (kt == ktiles - 1);
    const int nfa = lastt ? (w + 1) : 4;  // causal: skip fully-masked k-frags
    const int k0 = kt * 128;
    const int nb = cb ^ 1;

    // ---- issue next tile's loads (async; complete under compute) ----
    uint2 rowv[8];
    if (!lastt) {
      const int kn = k0 + 128;
#pragma unroll
      for (int r = 0; r < 8; ++r)
        rowv[r] = *(const uint2*)(Vp + (size_t)(kn + kbase + r) * 64 + dbase);
#pragma unroll
      for (int c = 0; c < 4; ++c) {
        int rb = w * 32 + c * 8;
        gll16(Kp + (size_t)(kn + rb + ksr) * 64 + kso, &Kls[nb][rb][0]);
      }
    }

    // ---- QK^T (swapped): S^T[k][q], 32x32 frags; lane owns q-col qrow ----
    f32x16 s[4] = {};
#pragma unroll
    for (int fa = 0; fa < 4; ++fa) {
      if (fa < nfa) {
#pragma unroll
        for (int ds = 0; ds < 4; ++ds) {
          bf16x8 kf = *(const bf16x8*)&Kls[cb][fa * 32 + q32][(ds * 16 + hi * 8) ^ ksw];
          s[fa] = __builtin_amdgcn_mfma_f32_32x32x16_bf16(kf, qf[ds], s[fa], 0, 0, 0);
        }
      }
    }

    // ---- softmax: scale + mask + lane-local max (+1 shfl) ----
    float mloc = -3e38f;
#pragma unroll
    for (int fa = 0; fa < 4; ++fa) {
      if (fa < nfa) {
#pragma unroll
        for (int r = 0; r < 16; ++r) {
          float v = s[fa][r] * sc;
          if (lastt && fa == w) {
            int km = (r & 3) + 8 * (r >> 2) + 4 * hi;
            if (km > q32) v = -3e38f;
          }
          s[fa][r] = v;
          mloc = fmaxf(mloc, v);
        }
      }
    }
    mloc = fmaxf(mloc, __shfl_xor(mloc, 32, 64));
    if (!__all(mloc <= m_run + 8.0f)) {  // defer-max (T13)
      float mnew = fmaxf(m_run, mloc);
      float rs = __builtin_amdgcn_exp2f(m_run - mnew);
      m_run = mnew;
      l_run *= rs;
      o_acc[0] *= rs;
      o_acc[1] *= rs;
    }

    // ---- write next V^T tile (vmcnt wait is cheap here; drains under PV) ----
    if (!lastt) {
#pragma unroll
      for (int dd = 0; dd < 4; ++dd) {
        u32 sel = (dd & 1) ? 0x07060302u : 0x05040100u;
        u32 a0 = (dd >> 1) ? rowv[0].y : rowv[0].x;
        u32 a1 = (dd >> 1) ? rowv[1].y : rowv[1].x;
        u32 a2 = (dd >> 1) ? rowv[2].y : rowv[2].x;
        u32 a3 = (dd >> 1) ? rowv[3].y : rowv[3].x;
        u32 a4 = (dd >> 1) ? rowv[4].y : rowv[4].x;
        u32 a5 = (dd >> 1) ? rowv[5].y : rowv[5].x;
        u32 a6 = (dd >> 1) ? rowv[6].y : rowv[6].x;
        u32 a7 = (dd >> 1) ? rowv[7].y : rowv[7].x;
        int4 val;
        val.x = __builtin_amdgcn_perm(a1, a0, sel);
        val.y = __builtin_amdgcn_perm(a3, a2, sel);
        val.z = __builtin_amdgcn_perm(a5, a4, sel);
        val.w = __builtin_amdgcn_perm(a7, a6, sel);
        int d = dbase + dd;
        int key = ((d & 7) ^ ((d >> 2) & 7)) << 3;
        *(int4*)&Vt[nb][d][kbase ^ key] = val;
      }
    }

    // ---- exp + in-register P-frag build (pack + shfl_xor exchange) + PV ----
    float lsum = 0.f;
#pragma unroll
    for (int fa = 0; fa < 4; ++fa) {
      if (fa < nfa) {
        float p[16];
#pragma unroll
        for (int r = 0; r < 16; ++r) {
          p[r] = __builtin_amdgcn_exp2f(s[fa][r] - m_run);
          lsum += p[r];
        }
        u32 x0 = pack2(p[0], p[1]),   x1 = pack2(p[2], p[3]);
        u32 x2 = pack2(p[4], p[5]),   x3 = pack2(p[6], p[7]);
        u32 y0 = pack2(p[8], p[9]),   y1 = pack2(p[10], p[11]);
        u32 y2 = pack2(p[12], p[13]), y3 = pack2(p[14], p[15]);
        u32 z0 = hi ? x0 : x2;
        u32 z1 = hi ? x1 : x3;
        u32 z2 = hi ? y0 : y2;
        u32 z3 = hi ? y1 : y3;
        z0 = (u32)__shfl_xor((int)z0, 32, 64);
        z1 = (u32)__shfl_xor((int)z1, 32, 64);
        z2 = (u32)__shfl_xor((int)z2, 32, 64);
        z3 = (u32)__shfl_xor((int)z3, 32, 64);
        u32x4 pw0 = hi ? (u32x4){z0, z1, x2, x3} : (u32x4){x0, x1, z0, z1};
        u32x4 pw1 = hi ? (u32x4){z2, z3, y2, y3} : (u32x4){y0, y1, z2, z3};
        bf16x8 P0 = __builtin_bit_cast(bf16x8, pw0);
        bf16x8 P1 = __builtin_bit_cast(bf16x8, pw1);
#pragma unroll
        for (int db = 0; db < 2; ++db) {
          int d = db * 32 + q32;
          bf16x8 vf0 = *(const bf16x8*)&Vt[cb][d][(fa * 32 + hi * 8) ^ vkey];
          o_acc[db] = __builtin_amdgcn_mfma_f32_32x32x16_bf16(vf0, P0, o_acc[db], 0, 0, 0);
          bf16x8 vf1 = *(const bf16x8*)&Vt[cb][d][(fa * 32 + 16 + hi * 8) ^ vkey];
          o_acc[db] = __builtin_amdgcn_mfma_f32_32x32x16_bf16(vf1, P1, o_acc[db], 0, 0, 0);
        }
      }
    }
    lsum += __shfl_xor(lsum, 32, 64);
    l_run += lsum;

    __syncthreads();  // buf nb fully staged; all reads of cb done
    cb = nb;
  }  // kt

  // ---- epilogue: lane owns column q=qrow; d = db*32 + rg*8 + hi*4 + 0..3 ----
  float inv = 1.0f / l_run;
  bf16_t* obase = Ob + ((size_t)(b * 2048 + qrow)) * 1024 + h * 64;
#pragma unroll
  for (int db = 0; db < 2; ++db) {
#pragma unroll
    for (int rg = 0; rg < 4; ++rg) {
      bf16x4 ov = {(bf16_t)(o_acc[db][rg * 4 + 0] * inv),
                   (bf16_t)(o_acc[db][rg * 4 + 1] * inv),
                   (bf16_t)(o_acc[db][rg * 4 + 2] * inv),
                   (bf16_t)(o_acc[db][rg * 4 + 3] * inv)};
      *(bf16x4*)(obase + db * 32 + rg * 8 + hi * 4) = ov;
    }
  }
}

// ---------------------------------------------------------------------------
extern "C" void kernel_launch(void* const* d_in, const int* in_sizes, int n_in,
                              void* d_out, int out_size, void* d_ws, size_t ws_size,
                              hipStream_t stream) {
  const float* x      = (const float*)d_in[0];
  const float* W_attn = (const float*)d_in[1];
  const float* b_attn = (const float*)d_in[2];
  const float* A_attn = (const float*)d_in[3];
  const float* B_attn = (const float*)d_in[4];
  const float* W_proj = (const float*)d_in[5];
  const float* b_proj = (const float*)d_in[6];
  const float* A_proj = (const float*)d_in[7];
  const float* B_proj = (const float*)d_in[8];
  float* out = (float*)d_out;

  char* ws = (char*)d_ws;
  bf16_t* WaE = (bf16_t*)(ws);               // 3072*1024*2
  bf16_t* WpE = (bf16_t*)(ws + 6291456);     // 1024*1024*2
  bf16_t* Xb  = (bf16_t*)(ws + 8388608);     // 4096*1024*2
  bf16_t* Qb  = (bf16_t*)(ws + 16777216);    // [B*H][T][64]
  bf16_t* Kb  = (bf16_t*)(ws + 25165824);
  bf16_t* Vb  = (bf16_t*)(ws + 33554432);
  bf16_t* Ob  = (bf16_t*)(ws + 41943040);    // [B*T][C] bf16

  prep_weff2<<<16384, 256, 0, stream>>>(W_attn, B_attn, A_attn, W_proj, B_proj, A_proj, WaE, WpE);
  cast_bf4<<<4096, 256, 0, stream>>>((const float4*)x, (bf16x4*)Xb, 1048576);

  gemm_bt<true><<<dim3(32, 24), 256, 0, stream>>>(Xb, WaE, b_attn, Qb, Kb, Vb, nullptr);
  attn_fwd<<<512, 256, 0, stream>>>(Qb, Kb, Vb, Ob);
  gemm_bt<false><<<dim3(32, 8), 256, 0, stream>>>(Ob, WpE, b_proj, nullptr, nullptr, nullptr, out);
}